// Round 4
// baseline (718.259 us; speedup 1.0000x reference)
//
#include <hip/hip_runtime.h>
#include <stdint.h>

typedef __attribute__((ext_vector_type(8))) short short8;    // MFMA A/B frag (8 bf16)
typedef __attribute__((ext_vector_type(4))) float floatx4;   // MFMA C/D frag

// ---------- bf16 helpers ----------
static __device__ __forceinline__ float b2f(uint16_t b){
    return __uint_as_float(((uint32_t)b) << 16);
}
static __device__ __forceinline__ uint16_t f2b(float f){
    uint32_t u = __float_as_uint(f);
    return (uint16_t)((u + 0x7fffu + ((u >> 16) & 1u)) >> 16);
}
static __device__ __forceinline__ float blo(uint32_t v){ return __uint_as_float(v << 16); }
static __device__ __forceinline__ float bhi(uint32_t v){ return __uint_as_float(v & 0xffff0000u); }
static __device__ __forceinline__ uint32_t pack2(float a, float b){
    return ((uint32_t)f2b(b) << 16) | (uint32_t)f2b(a);
}

// ---------- sentinel (only used when ws too small) ----------
__global__ void k_sentinel(uint32_t* out, int nwords, uint32_t pat){
    int i = blockIdx.x * blockDim.x + threadIdx.x;
    if (i < nwords) out[i] = pat;
}

// ---------- fused: zero deg[N] + dtype flags (flags block is blockIdx==ZB) ----------
__global__ void k_zf(int* deg, int N, const uint32_t* xw, const int* ei, int* flags, int ZB){
    if ((int)blockIdx.x == ZB){
        if (threadIdx.x != 0) return;
        int odd_nz = 0;
        for (int k = 0; k < 128; k++){
            if (ei[2 * k + 1] != 0) odd_nz = 1;
        }
        flags[0] = odd_nz ? 0 : 1;
        int big = 0;
        for (int k = 0; k < 128; k++){
            float lo = __uint_as_float(xw[k] << 16);
            if (!(fabsf(lo) <= 1024.0f)) big = 1;
        }
        flags[1] = big ? 0 : 1;
        return;
    }
    int i = blockIdx.x * blockDim.x + threadIdx.x;
    if (i < N) deg[i] = 0;
}

// ---------- CSR build: degree count + per-edge rank (rank makes k_fill atomic-free) ----------
__global__ void k_deg(const int* ei, int E, int* deg, uint16_t* rank, const int* flags){
    int e = blockIdx.x * blockDim.x + threadIdx.x;
    if (e < E){
        int d = flags[0] ? ei[2 * e] : ei[e];
        int r = atomicAdd(&deg[d], 1);
        rank[e] = (uint16_t)r;
    }
}

__global__ void k_scan1(const int* deg, int N, int* bsum){
    __shared__ int s[256];
    int t = threadIdx.x;
    int i = blockIdx.x * 256 + t;
    s[t] = (i < N) ? deg[i] : 0;
    __syncthreads();
    for (int off = 128; off > 0; off >>= 1){
        if (t < off) s[t] += s[t + off];
        __syncthreads();
    }
    if (t == 0) bsum[blockIdx.x] = s[0];
}

__global__ void k_scan2(int* bsum, int nb, int* rp, int N){
    __shared__ int s[512];
    int t = threadIdx.x;
    int v = (t < nb) ? bsum[t] : 0;
    s[t] = v;
    __syncthreads();
    for (int off = 1; off < 512; off <<= 1){
        int u = (t >= off) ? s[t - off] : 0;
        __syncthreads();
        s[t] += u;
        __syncthreads();
    }
    if (t < nb) bsum[t] = s[t] - v;
    if (t == 511) rp[N] = s[511];
}

__global__ void k_scan3(const int* deg, int N, const int* bpre, int* rp){
    __shared__ int s[256];
    int t = threadIdx.x;
    int i = blockIdx.x * 256 + t;
    int v = (i < N) ? deg[i] : 0;
    s[t] = v;
    __syncthreads();
    for (int off = 1; off < 256; off <<= 1){
        int u = (t >= off) ? s[t - off] : 0;
        __syncthreads();
        s[t] += u;
        __syncthreads();
    }
    if (i < N) rp[i] = bpre[blockIdx.x] + s[t] - v;
}

// ---------- fill: atomic-free, XCD-dst-sharded ----------
// Block b assumes XCD (b&7); the 8 blocks sharing edge-chunk (b>>3) each keep edges whose
// dst falls in their N/8 range, so all stores to a 64B line of col[] come from ONE XCD's
// L2 (kills the 18x write amplification seen in round 0). ei re-reads ride L3.
__global__ __launch_bounds__(256) void k_fill(const int* __restrict__ ei, int E,
                                              const int* __restrict__ rp,
                                              const uint16_t* __restrict__ rank,
                                              int* __restrict__ col,
                                              const int* __restrict__ flags, int N){
    int xcd = blockIdx.x & 7;
    int sub = blockIdx.x >> 3;
    int nsub = gridDim.x >> 3;
    int r0 = (int)(((long long)N * xcd) >> 3);
    int r1 = (int)(((long long)N * (xcd + 1)) >> 3);
    int e0 = (int)(((long long)E * sub) / nsub);
    int e1 = (int)(((long long)E * (sub + 1)) / nsub);
    int is64 = flags[0];
    for (int e = e0 + threadIdx.x; e < e1; e += 256){
        int d = is64 ? ei[2 * e] : ei[e];
        if (d >= r0 && d < r1){
            int sv = is64 ? ei[2 * (E + e)] : ei[E + e];
            int p = rp[d] + (int)rank[e];
            col[p] = sv;   // plain store: local L2 write-combines the line
        }
    }
}

// ---------- fused prep: W fragment reorders + bias cvt + x cvt in ONE launch ----------
// blocks [0,216): weight frags; [216,218): bias; [218,...): x f32->bf16 vectorized
__global__ void k_prep(const void* W0, const void* W1, const void* W2, const void* Wl,
                       uint16_t* Wf0, uint16_t* Wf1, uint16_t* Wf2, uint16_t* Wfl,
                       const void* b0, const void* b1, const void* b2, const void* bl,
                       float* bc, const void* x, uint16_t* hx, int NF,
                       const int* flags){
    int blk = blockIdx.x;
    int t = threadIdx.x;
    if (blk >= 218){
        if (flags[1]) return;   // layer-0 k_ag reads raw x directly in bf16 case
        int nb = gridDim.x - 218;
        int n8 = NF >> 3;       // NF is a multiple of 8 (F=128)
        const float4* xv = (const float4*)x;
        uint4* hv = (uint4*)hx;
        for (int i = (blk - 218) * 256 + t; i < n8; i += nb * 256){
            float4 u0 = xv[i * 2];
            float4 u1 = xv[i * 2 + 1];
            uint4 o;
            o.x = pack2(u0.x, u0.y); o.y = pack2(u0.z, u0.w);
            o.z = pack2(u1.x, u1.y); o.w = pack2(u1.z, u1.w);
            hv[i] = o;
        }
        return;
    }
    if (blk >= 216){
        int i = (blk - 216) * 256 + t;
        if (i >= 424) return;
        const void* src; int li;
        if (i < 128)      { src = b0; li = i; }
        else if (i < 256) { src = b1; li = i - 128; }
        else if (i < 384) { src = b2; li = i - 256; }
        else              { src = bl; li = i - 384; }
        bc[i] = flags[1] ? b2f(((const uint16_t*)src)[li]) : ((const float*)src)[li];
        return;
    }
    const void* W; uint16_t* Wf; int C, ntiles, lb;
    if (blk < 64)        { W = W0; Wf = Wf0; C = 128; ntiles = 8; lb = blk; }
    else if (blk < 128)  { W = W1; Wf = Wf1; C = 128; ntiles = 8; lb = blk - 64; }
    else if (blk < 192)  { W = W2; Wf = Wf2; C = 128; ntiles = 8; lb = blk - 128; }
    else                 { W = Wl; Wf = Wfl; C = 40;  ntiles = 3; lb = blk - 192; }
    int idx = lb * 256 + t;
    int total = 4 * ntiles * 512;
    if (idx >= total) return;
    int j = idx & 7;
    int lane = (idx >> 3) & 63;
    int nt = (idx >> 9) % ntiles;
    int kt = idx / (512 * ntiles);
    int k = kt * 32 + (lane >> 4) * 8 + j;
    int n = nt * 16 + (lane & 15);
    uint16_t v = 0;
    if (n < C){
        v = flags[1] ? ((const uint16_t*)W)[k * C + n]
                     : f2b(((const float*)W)[k * C + n]);
    }
    Wf[idx] = v;
}

// ---------- FUSED aggregate + MFMA GEMM + bias + stats partials ----------
// Block = 256 threads = one 16-row tile. Phase 1 (proven round-2 gather): thread
// (r = t>>4, c = t&15) accumulates a[8] = features [c*8,+8) of aggregated row r with
// lazy BN+ReLU on read. Phase 2: tile bounces through 4KB XOR-swizzled LDS into MFMA
// A-frag layout; 8 MFMA per wave (2 n-tiles x 4 k-tiles); B-frags read straight from
// the L2-hot 32KB Wf (LDS-staging would double that traffic). Saves the 51.2MB
// ag-write + re-read per layer and 1 dispatch per layer vs the split version.
__global__ __launch_bounds__(256) void k_ag(const uint16_t* __restrict__ Yin,
                                            const uint16_t* __restrict__ xraw,
                                            const int* __restrict__ rp,
                                            const int* __restrict__ col,
                                            uint16_t* __restrict__ Yout,
                                            const uint16_t* __restrict__ Wf,
                                            const float* __restrict__ bias,
                                            float* __restrict__ part, int N,
                                            const float* __restrict__ st,
                                            int apply_bn, float ninv,
                                            const int* __restrict__ flags){
    __shared__ __align__(16) uint16_t albs[2048];   // 16 x 128 bf16, XOR-swizzled
    __shared__ float sh_sum[128], sh_ssq[128];
    int t = threadIdx.x;
    if (t < 128){ sh_sum[t] = 0.f; sh_ssq[t] = 0.f; }
    int l16 = t & 15;
    int r = t >> 4;
    int row = blockIdx.x * 16 + r;
    int i = (row < N) ? row : N - 1;    // clamp (no early return: block syncs below)
    float tt[8], iv[8];
    const uint16_t* src = Yin;
    if (apply_bn){
        int f0 = l16 * 8;
        #pragma unroll
        for (int j = 0; j < 8; j++){
            float sv = st[f0 + j];
            float qv = st[128 + f0 + j];
            float m = sv * ninv;
            float var = qv * ninv - m * m;
            float ivj = rsqrtf(var + 1e-5f);
            iv[j] = ivj;
            tt[j] = -m * ivj;
        }
    } else if (flags[1]){
        src = xraw;
    }
    const uint4* base = (const uint4*)src;
    int s0 = rp[i], e0 = rp[i + 1];
    float a[8];
    {   // self loop (peeled out of the neighbor loop)
        uint4 w = base[(size_t)i * 16 + l16];
        a[0] = blo(w.x); a[1] = bhi(w.x); a[2] = blo(w.y); a[3] = bhi(w.y);
        a[4] = blo(w.z); a[5] = bhi(w.z); a[6] = blo(w.w); a[7] = bhi(w.w);
        if (apply_bn){
            #pragma unroll
            for (int jj = 0; jj < 8; jj++) a[jj] = fmaxf(fmaf(a[jj], iv[jj], tt[jj]), 0.f);
        }
    }
    int k = s0;
    for (; k + 3 < e0; k += 4){     // 4 independent row gathers in flight (round-2 proven)
        int j0 = col[k], j1 = col[k + 1], j2 = col[k + 2], j3 = col[k + 3];
        uint4 ww[4];
        ww[0] = base[(size_t)j0 * 16 + l16];
        ww[1] = base[(size_t)j1 * 16 + l16];
        ww[2] = base[(size_t)j2 * 16 + l16];
        ww[3] = base[(size_t)j3 * 16 + l16];
        #pragma unroll
        for (int u = 0; u < 4; u++){
            float v[8] = {blo(ww[u].x), bhi(ww[u].x), blo(ww[u].y), bhi(ww[u].y),
                          blo(ww[u].z), bhi(ww[u].z), blo(ww[u].w), bhi(ww[u].w)};
            if (apply_bn){
                #pragma unroll
                for (int jj = 0; jj < 8; jj++) v[jj] = fmaxf(fmaf(v[jj], iv[jj], tt[jj]), 0.f);
            }
            #pragma unroll
            for (int jj = 0; jj < 8; jj++) a[jj] += v[jj];
        }
    }
    for (; k < e0; k++){            // remainder 0..3 edges
        int j = col[k];
        uint4 w = base[(size_t)j * 16 + l16];
        float v[8] = {blo(w.x), bhi(w.x), blo(w.y), bhi(w.y),
                      blo(w.z), bhi(w.z), blo(w.w), bhi(w.w)};
        if (apply_bn){
            #pragma unroll
            for (int jj = 0; jj < 8; jj++) v[jj] = fmaxf(fmaf(v[jj], iv[jj], tt[jj]), 0.f);
        }
        #pragma unroll
        for (int jj = 0; jj < 8; jj++) a[jj] += v[jj];
    }
    {   // pack to bf16 and drop into swizzled LDS (row r, bytes [l16*16,+16))
        uint4 o;
        o.x = pack2(a[0], a[1]); o.y = pack2(a[2], a[3]);
        o.z = pack2(a[4], a[5]); o.w = pack2(a[6], a[7]);
        int wb = r * 256 + ((l16 * 16) ^ ((r & 7) << 4));
        *(uint4*)((char*)albs + wb) = o;
    }
    __syncthreads();
    // ---- MFMA phase: wave w computes n-tiles {2w, 2w+1} of the 16x128 output ----
    int lane = t & 63, wave = t >> 6;
    int m = lane & 15, q = lane >> 4;
    short8 af[4];
    #pragma unroll
    for (int kt = 0; kt < 4; kt++){
        int rb = m * 256 + ((kt * 64 + q * 16) ^ ((m & 7) << 4));
        af[kt] = *(const short8*)((const char*)albs + rb);
    }
    const short8* wg = (const short8*)Wf;
    floatx4 acc[2];
    acc[0] = (floatx4){0.f, 0.f, 0.f, 0.f};
    acc[1] = (floatx4){0.f, 0.f, 0.f, 0.f};
    #pragma unroll
    for (int kt = 0; kt < 4; kt++){
        #pragma unroll
        for (int n2 = 0; n2 < 2; n2++){
            short8 bf = wg[(kt * 8 + wave * 2 + n2) * 64 + lane];
            acc[n2] = __builtin_amdgcn_mfma_f32_16x16x32_bf16(af[kt], bf, acc[n2], 0, 0, 0);
        }
    }
    int row_base = blockIdx.x * 16;
    #pragma unroll
    for (int n2 = 0; n2 < 2; n2++){
        int ccol = (wave * 2 + n2) * 16 + m;
        float bv = bias[ccol];
        float s = 0.f, ss = 0.f;
        #pragma unroll
        for (int rr = 0; rr < 4; rr++){
            int grow = row_base + q * 4 + rr;
            if (grow < N){
                float y = acc[n2][rr] + bv;
                Yout[(size_t)grow * 128 + ccol] = f2b(y);
                s += y;
                ss += y * y;
            }
        }
        s += __shfl_xor(s, 16); s += __shfl_xor(s, 32);
        ss += __shfl_xor(ss, 16); ss += __shfl_xor(ss, 32);
        if (q == 0){
            atomicAdd(&sh_sum[ccol], s);
            atomicAdd(&sh_ssq[ccol], ss);
        }
    }
    __syncthreads();
    if (t < 128){
        part[(size_t)blockIdx.x * 256 + t] = sh_sum[t];
        part[(size_t)blockIdx.x * 256 + 128 + t] = sh_ssq[t];
    }
}

// ---------- reduce per-block partials -> st[256], column-sharded across 8 blocks ----------
__global__ __launch_bounds__(256) void k_red(const float* __restrict__ part, int nb,
                                             float* __restrict__ st){
    __shared__ float sh[256];
    int t = threadIdx.x;
    int c = t & 31, seg = t >> 5;           // 32 cols/block, 8 segments
    int cc = blockIdx.x * 32 + c;
    float s0 = 0.f, s1 = 0.f;
    int b = seg;
    for (; b + 8 < nb; b += 16){            // 2 independent loads in flight
        s0 += part[(size_t)b * 256 + cc];
        s1 += part[(size_t)(b + 8) * 256 + cc];
    }
    for (; b < nb; b += 8) s0 += part[(size_t)b * 256 + cc];
    sh[t] = s0 + s1;
    __syncthreads();
    if (t < 128) sh[t] += sh[t + 128];
    __syncthreads();
    if (t < 64) sh[t] += sh[t + 64];
    __syncthreads();
    if (t < 32) st[cc] = sh[t] + sh[t + 32];
}

// ---------- final GEMM with BN+ReLU applied to A on read ----------
__global__ __launch_bounds__(256) void k_out(const uint16_t* __restrict__ A,
                                             const uint16_t* __restrict__ Wf,
                                             const float* __restrict__ bias,
                                             const float* __restrict__ st, float ninv,
                                             void* __restrict__ out, int N,
                                             const int* __restrict__ flags){
    __shared__ __align__(16) uint16_t wlds[6144];
    __shared__ float s_m[128], s_iv[128];
    int t = threadIdx.x;
    {
        const uint4* s = (const uint4*)Wf;
        uint4* d = (uint4*)wlds;
        for (int i = t; i < 768; i += 256) d[i] = s[i];
    }
    if (t < 128){
        float m = st[t] * ninv;
        float var = st[128 + t] * ninv - m * m;
        s_m[t] = m;
        s_iv[t] = rsqrtf(var + 1e-5f);
    }
    __syncthreads();
    int lane = t & 63, wave = t >> 6;
    int m = lane & 15, q = lane >> 4;
    int row_base = blockIdx.x * 64 + wave * 16;
    int arow = row_base + m;
    if (arow >= N) arow = N - 1;
    short8 afrag[4];
    const uint4* ap = (const uint4*)(A + (size_t)arow * 128);
    #pragma unroll
    for (int kt = 0; kt < 4; kt++){
        uint4 u = ap[kt * 4 + q];
        float v[8] = {blo(u.x), bhi(u.x), blo(u.y), bhi(u.y),
                      blo(u.z), bhi(u.z), blo(u.w), bhi(u.w)};
        int c0 = kt * 32 + q * 8;
        #pragma unroll
        for (int j = 0; j < 8; j++) v[j] = fmaxf((v[j] - s_m[c0 + j]) * s_iv[c0 + j], 0.f);
        uint4 o;
        o.x = pack2(v[0], v[1]); o.y = pack2(v[2], v[3]);
        o.z = pack2(v[4], v[5]); o.w = pack2(v[6], v[7]);
        afrag[kt] = *(short8*)&o;
    }
    floatx4 acc[3];
    #pragma unroll
    for (int nt = 0; nt < 3; nt++) acc[nt] = (floatx4){0.f, 0.f, 0.f, 0.f};
    const short8* wl = (const short8*)wlds;
    #pragma unroll
    for (int kt = 0; kt < 4; kt++){
        #pragma unroll
        for (int nt = 0; nt < 3; nt++){
            acc[nt] = __builtin_amdgcn_mfma_f32_16x16x32_bf16(afrag[kt], wl[(kt * 3 + nt) * 64 + lane], acc[nt], 0, 0, 0);
        }
    }
    int isbf = flags[1];
    #pragma unroll
    for (int nt = 0; nt < 3; nt++){
        int ccol = nt * 16 + m;
        if (ccol < 40){
            float bv = bias[ccol];
            #pragma unroll
            for (int r = 0; r < 4; r++){
                int grow = row_base + q * 4 + r;
                if (grow < N){
                    float y = acc[nt][r] + bv;
                    if (isbf) ((uint16_t*)out)[(size_t)grow * 40 + ccol] = f2b(y);
                    else      ((float*)out)[(size_t)grow * 40 + ccol] = y;
                }
            }
        }
    }
}

extern "C" void kernel_launch(void* const* d_in, const int* in_sizes, int n_in,
                              void* d_out, int out_size, void* d_ws, size_t ws_size,
                              hipStream_t stream){
    (void)n_in;
    const void* x  = d_in[0];
    const int* ei  = (const int*)d_in[1];
    const void* W0 = d_in[2];
    const void* b0 = d_in[3];
    const void* W1 = d_in[4];
    const void* b1 = d_in[5];
    const void* W2 = d_in[6];
    const void* b2 = d_in[7];
    const void* Wl = d_in[8];
    const void* bl = d_in[9];

    const int N = in_sizes[0] / 128;
    const int E = in_sizes[1] / 2;
    const int NF = N * 128;
    const int NB = (N + 255) / 256;
    const int agg_blocks  = (N + 15) / 16;      // fused agg+gemm blocks (16 rows each)
    const int gemm_blocks = (N + 63) / 64;      // k_out blocks

    // ---- workspace layout ----
    char* ws = (char*)d_ws;
    size_t off = 0;
    uint16_t* hx = (uint16_t*)(ws + off); off += ((size_t)NF * 2 + 255) & ~(size_t)255;
    uint16_t* ag = (uint16_t*)(ws + off); off += ((size_t)NF * 2 + 255) & ~(size_t)255;
    int* col     = (int*)(ws + off);      off += ((size_t)E * 4 + 255) & ~(size_t)255;
    int* rp      = (int*)(ws + off);      off += ((size_t)(N + 1) * 4 + 255) & ~(size_t)255;
    uint16_t* rank = (uint16_t*)(ws + off); off += ((size_t)E * 2 + 255) & ~(size_t)255;
    int* deg     = (int*)(ws + off);      off += ((size_t)N * 4 + 255) & ~(size_t)255;
    int* bsum    = (int*)(ws + off);      off += 512 * 4;
    int* flags   = (int*)(ws + off);      off += 256;
    uint16_t* Wf0 = (uint16_t*)(ws + off); off += 16384 * 2;
    uint16_t* Wf1 = (uint16_t*)(ws + off); off += 16384 * 2;
    uint16_t* Wf2 = (uint16_t*)(ws + off); off += 16384 * 2;
    uint16_t* Wfl = (uint16_t*)(ws + off); off += 6144 * 2;
    float* bc    = (float*)(ws + off);    off += 424 * 4 + 160;
    float* stats = (float*)(ws + off);    off += 768 * 4;   // 3 layers x (sum[128], ssq[128])
    float* part  = (float*)(ws + off);    off += (size_t)agg_blocks * 256 * 4;
    const size_t required = off;

    if (ws_size < required){
        int nwords = out_size / 2;
        k_sentinel<<<(nwords + 255) / 256, 256, 0, stream>>>((uint32_t*)d_out, nwords, 0x40004000u);
        return;
    }

    // ---- flags + zero deg (fused), CSR build ----
    k_zf<<<NB + 1, 256, 0, stream>>>(deg, N, (const uint32_t*)x, ei, flags, NB);
    k_deg<<<(E + 255) / 256, 256, 0, stream>>>(ei, E, deg, rank, flags);
    k_scan1<<<NB, 256, 0, stream>>>(deg, N, bsum);
    k_scan2<<<1, 512, 0, stream>>>(bsum, NB, rp, N);
    k_scan3<<<NB, 256, 0, stream>>>(deg, N, bsum, rp);
    k_fill<<<1024, 256, 0, stream>>>(ei, E, rp, rank, col, flags, N);

    // ---- fused conversions / weight prep ----
    k_prep<<<2266, 256, 0, stream>>>(W0, W1, W2, Wl, Wf0, Wf1, Wf2, Wfl,
                                     b0, b1, b2, bl, bc, x, hx, NF, flags);

    const float ninv = 1.0f / (float)N;
    const uint16_t* xr = (const uint16_t*)x;

    // layer 0: Y0 = agg(x) @ W0 + b0  -> ag, stats0
    k_ag<<<agg_blocks, 256, 0, stream>>>(hx, xr, rp, col, ag, Wf0, bc, part, N,
                                         stats, 0, ninv, flags);
    k_red<<<8, 256, 0, stream>>>(part, agg_blocks, stats);
    // layer 1: Y1 = agg(bn0(Y0)) @ W1 + b1 -> hx, stats1
    k_ag<<<agg_blocks, 256, 0, stream>>>(ag, xr, rp, col, hx, Wf1, bc + 128, part, N,
                                         stats, 1, ninv, flags);
    k_red<<<8, 256, 0, stream>>>(part, agg_blocks, stats + 256);
    // layer 2: Y2 = agg(bn1(Y1)) @ W2 + b2 -> ag, stats2
    k_ag<<<agg_blocks, 256, 0, stream>>>(hx, xr, rp, col, ag, Wf2, bc + 256, part, N,
                                         stats + 256, 1, ninv, flags);
    k_red<<<8, 256, 0, stream>>>(part, agg_blocks, stats + 512);
    // final: out = bn2(Y2)relu @ Wl + bl
    k_out<<<gemm_blocks, 256, 0, stream>>>(ag, Wfl, bc + 384, stats + 512, ninv, d_out, N, flags);
}

// Round 5
// 373.725 us; speedup vs baseline: 1.9219x; 1.9219x over previous
//
#include <hip/hip_runtime.h>
#include <stdint.h>

typedef __attribute__((ext_vector_type(8))) short short8;    // MFMA A/B frag (8 bf16)
typedef __attribute__((ext_vector_type(4))) float floatx4;   // MFMA C/D frag

// ---------- bf16 helpers ----------
static __device__ __forceinline__ float b2f(uint16_t b){
    return __uint_as_float(((uint32_t)b) << 16);
}
static __device__ __forceinline__ uint16_t f2b(float f){
    uint32_t u = __float_as_uint(f);
    return (uint16_t)((u + 0x7fffu + ((u >> 16) & 1u)) >> 16);
}
static __device__ __forceinline__ float blo(uint32_t v){ return __uint_as_float(v << 16); }
static __device__ __forceinline__ float bhi(uint32_t v){ return __uint_as_float(v & 0xffff0000u); }
static __device__ __forceinline__ uint32_t pack2(float a, float b){
    return ((uint32_t)f2b(b) << 16) | (uint32_t)f2b(a);
}

// ---------- sentinel (only used when ws too small) ----------
__global__ void k_sentinel(uint32_t* out, int nwords, uint32_t pat){
    int i = blockIdx.x * blockDim.x + threadIdx.x;
    if (i < nwords) out[i] = pat;
}

// ---------- fused: zero deg[N] + zero stats[768] + dtype flags ----------
// blocks [0,ZB): zero deg; block ZB: flags; block ZB+1: zero stats (ws is poisoned)
__global__ void k_zf(int* deg, int N, const uint32_t* xw, const int* ei, int* flags,
                     float* stats, int ZB){
    if ((int)blockIdx.x == ZB){
        if (threadIdx.x != 0) return;
        int odd_nz = 0;
        for (int k = 0; k < 128; k++){
            if (ei[2 * k + 1] != 0) odd_nz = 1;
        }
        flags[0] = odd_nz ? 0 : 1;
        int big = 0;
        for (int k = 0; k < 128; k++){
            float lo = __uint_as_float(xw[k] << 16);
            if (!(fabsf(lo) <= 1024.0f)) big = 1;
        }
        flags[1] = big ? 0 : 1;
        return;
    }
    if ((int)blockIdx.x == ZB + 1){
        int t = threadIdx.x;
        #pragma unroll
        for (int j = 0; j < 3; j++) stats[j * 256 + t] = 0.f;
        return;
    }
    int i = blockIdx.x * blockDim.x + threadIdx.x;
    if (i < N) deg[i] = 0;
}

// ---------- CSR build: degree count + per-edge rank (rank makes k_fill atomic-free) ----------
__global__ void k_deg(const int* ei, int E, int* deg, uint16_t* rank, const int* flags){
    int e = blockIdx.x * blockDim.x + threadIdx.x;
    if (e < E){
        int d = flags[0] ? ei[2 * e] : ei[e];
        int r = atomicAdd(&deg[d], 1);
        rank[e] = (uint16_t)r;
    }
}

__global__ void k_scan1(const int* deg, int N, int* bsum){
    __shared__ int s[256];
    int t = threadIdx.x;
    int i = blockIdx.x * 256 + t;
    s[t] = (i < N) ? deg[i] : 0;
    __syncthreads();
    for (int off = 128; off > 0; off >>= 1){
        if (t < off) s[t] += s[t + off];
        __syncthreads();
    }
    if (t == 0) bsum[blockIdx.x] = s[0];
}

__global__ void k_scan2(int* bsum, int nb, int* rp, int N){
    __shared__ int s[512];
    int t = threadIdx.x;
    int v = (t < nb) ? bsum[t] : 0;
    s[t] = v;
    __syncthreads();
    for (int off = 1; off < 512; off <<= 1){
        int u = (t >= off) ? s[t - off] : 0;
        __syncthreads();
        s[t] += u;
        __syncthreads();
    }
    if (t < nb) bsum[t] = s[t] - v;
    if (t == 511) rp[N] = s[511];
}

__global__ void k_scan3(const int* deg, int N, const int* bpre, int* rp){
    __shared__ int s[256];
    int t = threadIdx.x;
    int i = blockIdx.x * 256 + t;
    int v = (i < N) ? deg[i] : 0;
    s[t] = v;
    __syncthreads();
    for (int off = 1; off < 256; off <<= 1){
        int u = (t >= off) ? s[t - off] : 0;
        __syncthreads();
        s[t] += u;
        __syncthreads();
    }
    if (i < N) rp[i] = bpre[blockIdx.x] + s[t] - v;
}

// ---------- fill: atomic-free, XCD-dst-sharded ----------
// Block b assumes XCD (b&7); the 8 blocks sharing edge-chunk (b>>3) each keep edges whose
// dst falls in their N/8 range, so all stores to a 64B line of col[] come from ONE XCD's
// L2 (kills the 18x write amplification seen in round 0). ei re-reads ride L3.
__global__ __launch_bounds__(256) void k_fill(const int* __restrict__ ei, int E,
                                              const int* __restrict__ rp,
                                              const uint16_t* __restrict__ rank,
                                              int* __restrict__ col,
                                              const int* __restrict__ flags, int N){
    int xcd = blockIdx.x & 7;
    int sub = blockIdx.x >> 3;
    int nsub = gridDim.x >> 3;
    int r0 = (int)(((long long)N * xcd) >> 3);
    int r1 = (int)(((long long)N * (xcd + 1)) >> 3);
    int e0 = (int)(((long long)E * sub) / nsub);
    int e1 = (int)(((long long)E * (sub + 1)) / nsub);
    int is64 = flags[0];
    for (int e = e0 + threadIdx.x; e < e1; e += 256){
        int d = is64 ? ei[2 * e] : ei[e];
        if (d >= r0 && d < r1){
            int sv = is64 ? ei[2 * (E + e)] : ei[E + e];
            int p = rp[d] + (int)rank[e];
            col[p] = sv;   // plain store: local L2 write-combines the line
        }
    }
}

// ---------- fused prep: W fragment reorders + bias cvt + x cvt in ONE launch ----------
// blocks [0,216): weight frags; [216,218): bias; [218,...): x f32->bf16 vectorized
__global__ void k_prep(const void* W0, const void* W1, const void* W2, const void* Wl,
                       uint16_t* Wf0, uint16_t* Wf1, uint16_t* Wf2, uint16_t* Wfl,
                       const void* b0, const void* b1, const void* b2, const void* bl,
                       float* bc, const void* x, uint16_t* hx, int NF,
                       const int* flags){
    int blk = blockIdx.x;
    int t = threadIdx.x;
    if (blk >= 218){
        if (flags[1]) return;   // layer-0 k_ag reads raw x directly in bf16 case
        int nb = gridDim.x - 218;
        int n8 = NF >> 3;       // NF is a multiple of 8 (F=128)
        const float4* xv = (const float4*)x;
        uint4* hv = (uint4*)hx;
        for (int i = (blk - 218) * 256 + t; i < n8; i += nb * 256){
            float4 u0 = xv[i * 2];
            float4 u1 = xv[i * 2 + 1];
            uint4 o;
            o.x = pack2(u0.x, u0.y); o.y = pack2(u0.z, u0.w);
            o.z = pack2(u1.x, u1.y); o.w = pack2(u1.z, u1.w);
            hv[i] = o;
        }
        return;
    }
    if (blk >= 216){
        int i = (blk - 216) * 256 + t;
        if (i >= 424) return;
        const void* src; int li;
        if (i < 128)      { src = b0; li = i; }
        else if (i < 256) { src = b1; li = i - 128; }
        else if (i < 384) { src = b2; li = i - 256; }
        else              { src = bl; li = i - 384; }
        bc[i] = flags[1] ? b2f(((const uint16_t*)src)[li]) : ((const float*)src)[li];
        return;
    }
    const void* W; uint16_t* Wf; int C, ntiles, lb;
    if (blk < 64)        { W = W0; Wf = Wf0; C = 128; ntiles = 8; lb = blk; }
    else if (blk < 128)  { W = W1; Wf = Wf1; C = 128; ntiles = 8; lb = blk - 64; }
    else if (blk < 192)  { W = W2; Wf = Wf2; C = 128; ntiles = 8; lb = blk - 128; }
    else                 { W = Wl; Wf = Wfl; C = 40;  ntiles = 3; lb = blk - 192; }
    int idx = lb * 256 + t;
    int total = 4 * ntiles * 512;
    if (idx >= total) return;
    int j = idx & 7;
    int lane = (idx >> 3) & 63;
    int nt = (idx >> 9) % ntiles;
    int kt = idx / (512 * ntiles);
    int k = kt * 32 + (lane >> 4) * 8 + j;
    int n = nt * 16 + (lane & 15);
    uint16_t v = 0;
    if (n < C){
        v = flags[1] ? ((const uint16_t*)W)[k * C + n]
                     : f2b(((const float*)W)[k * C + n]);
    }
    Wf[idx] = v;
}

// ---------- FUSED aggregate + MFMA GEMM + bias + stats partials ----------
// Block = 256 threads = one 16-row tile. Phase 1 (proven round-2 gather): thread
// (r = t>>4, c = t&15) accumulates a[8] = features [c*8,+8) of aggregated row r with
// lazy BN+ReLU on read. Phase 2: tile bounces through 4KB XOR-swizzled LDS into MFMA
// A-frag layout; 8 MFMA per wave (2 n-tiles x 4 k-tiles); B-frags read straight from
// the L2-hot 32KB Wf (LDS-staging would double that traffic). Saves the 51.2MB
// ag-write + re-read per layer and 1 dispatch per layer vs the split version.
__global__ __launch_bounds__(256) void k_ag(const uint16_t* __restrict__ Yin,
                                            const uint16_t* __restrict__ xraw,
                                            const int* __restrict__ rp,
                                            const int* __restrict__ col,
                                            uint16_t* __restrict__ Yout,
                                            const uint16_t* __restrict__ Wf,
                                            const float* __restrict__ bias,
                                            float* __restrict__ part, int N,
                                            const float* __restrict__ st,
                                            int apply_bn, float ninv,
                                            const int* __restrict__ flags){
    __shared__ __align__(16) uint16_t albs[2048];   // 16 x 128 bf16, XOR-swizzled
    __shared__ float sh_sum[128], sh_ssq[128];
    int t = threadIdx.x;
    if (t < 128){ sh_sum[t] = 0.f; sh_ssq[t] = 0.f; }
    int l16 = t & 15;
    int r = t >> 4;
    int row = blockIdx.x * 16 + r;
    int i = (row < N) ? row : N - 1;    // clamp (no early return: block syncs below)
    float tt[8], iv[8];
    const uint16_t* src = Yin;
    if (apply_bn){
        int f0 = l16 * 8;
        #pragma unroll
        for (int j = 0; j < 8; j++){
            float sv = st[f0 + j];
            float qv = st[128 + f0 + j];
            float m = sv * ninv;
            float var = qv * ninv - m * m;
            float ivj = rsqrtf(var + 1e-5f);
            iv[j] = ivj;
            tt[j] = -m * ivj;
        }
    } else if (flags[1]){
        src = xraw;
    }
    const uint4* base = (const uint4*)src;
    int s0 = rp[i], e0 = rp[i + 1];
    float a[8];
    {   // self loop (peeled out of the neighbor loop)
        uint4 w = base[(size_t)i * 16 + l16];
        a[0] = blo(w.x); a[1] = bhi(w.x); a[2] = blo(w.y); a[3] = bhi(w.y);
        a[4] = blo(w.z); a[5] = bhi(w.z); a[6] = blo(w.w); a[7] = bhi(w.w);
        if (apply_bn){
            #pragma unroll
            for (int jj = 0; jj < 8; jj++) a[jj] = fmaxf(fmaf(a[jj], iv[jj], tt[jj]), 0.f);
        }
    }
    int k = s0;
    for (; k + 3 < e0; k += 4){     // 4 independent row gathers in flight (round-2 proven)
        int j0 = col[k], j1 = col[k + 1], j2 = col[k + 2], j3 = col[k + 3];
        uint4 ww[4];
        ww[0] = base[(size_t)j0 * 16 + l16];
        ww[1] = base[(size_t)j1 * 16 + l16];
        ww[2] = base[(size_t)j2 * 16 + l16];
        ww[3] = base[(size_t)j3 * 16 + l16];
        #pragma unroll
        for (int u = 0; u < 4; u++){
            float v[8] = {blo(ww[u].x), bhi(ww[u].x), blo(ww[u].y), bhi(ww[u].y),
                          blo(ww[u].z), bhi(ww[u].z), blo(ww[u].w), bhi(ww[u].w)};
            if (apply_bn){
                #pragma unroll
                for (int jj = 0; jj < 8; jj++) v[jj] = fmaxf(fmaf(v[jj], iv[jj], tt[jj]), 0.f);
            }
            #pragma unroll
            for (int jj = 0; jj < 8; jj++) a[jj] += v[jj];
        }
    }
    for (; k < e0; k++){            // remainder 0..3 edges
        int j = col[k];
        uint4 w = base[(size_t)j * 16 + l16];
        float v[8] = {blo(w.x), bhi(w.x), blo(w.y), bhi(w.y),
                      blo(w.z), bhi(w.z), blo(w.w), bhi(w.w)};
        if (apply_bn){
            #pragma unroll
            for (int jj = 0; jj < 8; jj++) v[jj] = fmaxf(fmaf(v[jj], iv[jj], tt[jj]), 0.f);
        }
        #pragma unroll
        for (int jj = 0; jj < 8; jj++) a[jj] += v[jj];
    }
    {   // pack to bf16 and drop into swizzled LDS (row r, bytes [l16*16,+16))
        uint4 o;
        o.x = pack2(a[0], a[1]); o.y = pack2(a[2], a[3]);
        o.z = pack2(a[4], a[5]); o.w = pack2(a[6], a[7]);
        int wb = r * 256 + ((l16 * 16) ^ ((r & 7) << 4));
        *(uint4*)((char*)albs + wb) = o;
    }
    __syncthreads();
    // ---- MFMA phase: wave w computes n-tiles {2w, 2w+1} of the 16x128 output ----
    int lane = t & 63, wave = t >> 6;
    int m = lane & 15, q = lane >> 4;
    short8 af[4];
    #pragma unroll
    for (int kt = 0; kt < 4; kt++){
        int rb = m * 256 + ((kt * 64 + q * 16) ^ ((m & 7) << 4));
        af[kt] = *(const short8*)((const char*)albs + rb);
    }
    const short8* wg = (const short8*)Wf;
    floatx4 acc[2];
    acc[0] = (floatx4){0.f, 0.f, 0.f, 0.f};
    acc[1] = (floatx4){0.f, 0.f, 0.f, 0.f};
    #pragma unroll
    for (int kt = 0; kt < 4; kt++){
        #pragma unroll
        for (int n2 = 0; n2 < 2; n2++){
            short8 bf = wg[(kt * 8 + wave * 2 + n2) * 64 + lane];
            acc[n2] = __builtin_amdgcn_mfma_f32_16x16x32_bf16(af[kt], bf, acc[n2], 0, 0, 0);
        }
    }
    int row_base = blockIdx.x * 16;
    #pragma unroll
    for (int n2 = 0; n2 < 2; n2++){
        int ccol = (wave * 2 + n2) * 16 + m;
        float bv = bias[ccol];
        float s = 0.f, ss = 0.f;
        #pragma unroll
        for (int rr = 0; rr < 4; rr++){
            int grow = row_base + q * 4 + rr;
            if (grow < N){
                float y = acc[n2][rr] + bv;
                Yout[(size_t)grow * 128 + ccol] = f2b(y);
                s += y;
                ss += y * y;
            }
        }
        s += __shfl_xor(s, 16); s += __shfl_xor(s, 32);
        ss += __shfl_xor(ss, 16); ss += __shfl_xor(ss, 32);
        if (q == 0){
            atomicAdd(&sh_sum[ccol], s);
            atomicAdd(&sh_ssq[ccol], ss);
        }
    }
    __syncthreads();
    if (t < 128){
        part[(size_t)blockIdx.x * 256 + t] = sh_sum[t];
        part[(size_t)blockIdx.x * 256 + 128 + t] = sh_ssq[t];
    }
}

// ---------- reduce per-block partials -> st[256] ----------
// Flat grid: block b reduces rows [b*32, b*32+32) of part for ALL 256 columns.
// Thread t owns column t -> every row read is 256 threads x 4B = 1KB contiguous
// (fully coalesced). 4 accumulators for load ILP; one atomicAdd per thread into
// the pre-zeroed st. (Round-4's 8-block version was 124us at 0.35% occupancy --
// 1KB-strided latency-serialized reads. This shape is ~2TB/s.)
__global__ __launch_bounds__(256) void k_red(const float* __restrict__ part, int nb,
                                             float* __restrict__ st){
    int t = threadIdx.x;
    int r0 = blockIdx.x * 32;
    int r1 = r0 + 32; if (r1 > nb) r1 = nb;
    float s0 = 0.f, s1 = 0.f, s2 = 0.f, s3 = 0.f;
    int b = r0;
    for (; b + 3 < r1; b += 4){
        s0 += part[(size_t)b * 256 + t];
        s1 += part[(size_t)(b + 1) * 256 + t];
        s2 += part[(size_t)(b + 2) * 256 + t];
        s3 += part[(size_t)(b + 3) * 256 + t];
    }
    for (; b < r1; b++) s0 += part[(size_t)b * 256 + t];
    atomicAdd(&st[t], (s0 + s1) + (s2 + s3));
}

// ---------- final GEMM with BN+ReLU applied to A on read ----------
__global__ __launch_bounds__(256) void k_out(const uint16_t* __restrict__ A,
                                             const uint16_t* __restrict__ Wf,
                                             const float* __restrict__ bias,
                                             const float* __restrict__ st, float ninv,
                                             void* __restrict__ out, int N,
                                             const int* __restrict__ flags){
    __shared__ __align__(16) uint16_t wlds[6144];
    __shared__ float s_m[128], s_iv[128];
    int t = threadIdx.x;
    {
        const uint4* s = (const uint4*)Wf;
        uint4* d = (uint4*)wlds;
        for (int i = t; i < 768; i += 256) d[i] = s[i];
    }
    if (t < 128){
        float m = st[t] * ninv;
        float var = st[128 + t] * ninv - m * m;
        s_m[t] = m;
        s_iv[t] = rsqrtf(var + 1e-5f);
    }
    __syncthreads();
    int lane = t & 63, wave = t >> 6;
    int m = lane & 15, q = lane >> 4;
    int row_base = blockIdx.x * 64 + wave * 16;
    int arow = row_base + m;
    if (arow >= N) arow = N - 1;
    short8 afrag[4];
    const uint4* ap = (const uint4*)(A + (size_t)arow * 128);
    #pragma unroll
    for (int kt = 0; kt < 4; kt++){
        uint4 u = ap[kt * 4 + q];
        float v[8] = {blo(u.x), bhi(u.x), blo(u.y), bhi(u.y),
                      blo(u.z), bhi(u.z), blo(u.w), bhi(u.w)};
        int c0 = kt * 32 + q * 8;
        #pragma unroll
        for (int j = 0; j < 8; j++) v[j] = fmaxf((v[j] - s_m[c0 + j]) * s_iv[c0 + j], 0.f);
        uint4 o;
        o.x = pack2(v[0], v[1]); o.y = pack2(v[2], v[3]);
        o.z = pack2(v[4], v[5]); o.w = pack2(v[6], v[7]);
        afrag[kt] = *(short8*)&o;
    }
    floatx4 acc[3];
    #pragma unroll
    for (int nt = 0; nt < 3; nt++) acc[nt] = (floatx4){0.f, 0.f, 0.f, 0.f};
    const short8* wl = (const short8*)wlds;
    #pragma unroll
    for (int kt = 0; kt < 4; kt++){
        #pragma unroll
        for (int nt = 0; nt < 3; nt++){
            acc[nt] = __builtin_amdgcn_mfma_f32_16x16x32_bf16(afrag[kt], wl[(kt * 3 + nt) * 64 + lane], acc[nt], 0, 0, 0);
        }
    }
    int isbf = flags[1];
    #pragma unroll
    for (int nt = 0; nt < 3; nt++){
        int ccol = nt * 16 + m;
        if (ccol < 40){
            float bv = bias[ccol];
            #pragma unroll
            for (int r = 0; r < 4; r++){
                int grow = row_base + q * 4 + r;
                if (grow < N){
                    float y = acc[nt][r] + bv;
                    if (isbf) ((uint16_t*)out)[(size_t)grow * 40 + ccol] = f2b(y);
                    else      ((float*)out)[(size_t)grow * 40 + ccol] = y;
                }
            }
        }
    }
}

extern "C" void kernel_launch(void* const* d_in, const int* in_sizes, int n_in,
                              void* d_out, int out_size, void* d_ws, size_t ws_size,
                              hipStream_t stream){
    (void)n_in;
    const void* x  = d_in[0];
    const int* ei  = (const int*)d_in[1];
    const void* W0 = d_in[2];
    const void* b0 = d_in[3];
    const void* W1 = d_in[4];
    const void* b1 = d_in[5];
    const void* W2 = d_in[6];
    const void* b2 = d_in[7];
    const void* Wl = d_in[8];
    const void* bl = d_in[9];

    const int N = in_sizes[0] / 128;
    const int E = in_sizes[1] / 2;
    const int NF = N * 128;
    const int NB = (N + 255) / 256;
    const int agg_blocks  = (N + 15) / 16;      // fused agg+gemm blocks (16 rows each)
    const int gemm_blocks = (N + 63) / 64;      // k_out blocks
    const int red_blocks  = (agg_blocks + 31) / 32;

    // ---- workspace layout ----
    char* ws = (char*)d_ws;
    size_t off = 0;
    uint16_t* hx = (uint16_t*)(ws + off); off += ((size_t)NF * 2 + 255) & ~(size_t)255;
    uint16_t* ag = (uint16_t*)(ws + off); off += ((size_t)NF * 2 + 255) & ~(size_t)255;
    int* col     = (int*)(ws + off);      off += ((size_t)E * 4 + 255) & ~(size_t)255;
    int* rp      = (int*)(ws + off);      off += ((size_t)(N + 1) * 4 + 255) & ~(size_t)255;
    uint16_t* rank = (uint16_t*)(ws + off); off += ((size_t)E * 2 + 255) & ~(size_t)255;
    int* deg     = (int*)(ws + off);      off += ((size_t)N * 4 + 255) & ~(size_t)255;
    int* bsum    = (int*)(ws + off);      off += 512 * 4;
    int* flags   = (int*)(ws + off);      off += 256;
    uint16_t* Wf0 = (uint16_t*)(ws + off); off += 16384 * 2;
    uint16_t* Wf1 = (uint16_t*)(ws + off); off += 16384 * 2;
    uint16_t* Wf2 = (uint16_t*)(ws + off); off += 16384 * 2;
    uint16_t* Wfl = (uint16_t*)(ws + off); off += 6144 * 2;
    float* bc    = (float*)(ws + off);    off += 424 * 4 + 160;
    float* stats = (float*)(ws + off);    off += 768 * 4;   // 3 layers x (sum[128], ssq[128])
    float* part  = (float*)(ws + off);    off += (size_t)agg_blocks * 256 * 4;
    const size_t required = off;

    if (ws_size < required){
        int nwords = out_size / 2;
        k_sentinel<<<(nwords + 255) / 256, 256, 0, stream>>>((uint32_t*)d_out, nwords, 0x40004000u);
        return;
    }

    // ---- flags + zero deg + zero stats (fused), CSR build ----
    k_zf<<<NB + 2, 256, 0, stream>>>(deg, N, (const uint32_t*)x, ei, flags, stats, NB);
    k_deg<<<(E + 255) / 256, 256, 0, stream>>>(ei, E, deg, rank, flags);
    k_scan1<<<NB, 256, 0, stream>>>(deg, N, bsum);
    k_scan2<<<1, 512, 0, stream>>>(bsum, NB, rp, N);
    k_scan3<<<NB, 256, 0, stream>>>(deg, N, bsum, rp);
    k_fill<<<1024, 256, 0, stream>>>(ei, E, rp, rank, col, flags, N);

    // ---- fused conversions / weight prep ----
    k_prep<<<2266, 256, 0, stream>>>(W0, W1, W2, Wl, Wf0, Wf1, Wf2, Wfl,
                                     b0, b1, b2, bl, bc, x, hx, NF, flags);

    const float ninv = 1.0f / (float)N;
    const uint16_t* xr = (const uint16_t*)x;

    // layer 0: Y0 = agg(x) @ W0 + b0  -> ag, stats0
    k_ag<<<agg_blocks, 256, 0, stream>>>(hx, xr, rp, col, ag, Wf0, bc, part, N,
                                         stats, 0, ninv, flags);
    k_red<<<red_blocks, 256, 0, stream>>>(part, agg_blocks, stats);
    // layer 1: Y1 = agg(bn0(Y0)) @ W1 + b1 -> hx, stats1
    k_ag<<<agg_blocks, 256, 0, stream>>>(ag, xr, rp, col, hx, Wf1, bc + 128, part, N,
                                         stats, 1, ninv, flags);
    k_red<<<red_blocks, 256, 0, stream>>>(part, agg_blocks, stats + 256);
    // layer 2: Y2 = agg(bn1(Y1)) @ W2 + b2 -> ag, stats2
    k_ag<<<agg_blocks, 256, 0, stream>>>(hx, xr, rp, col, ag, Wf2, bc + 256, part, N,
                                         stats + 256, 1, ninv, flags);
    k_red<<<red_blocks, 256, 0, stream>>>(part, agg_blocks, stats + 512);
    // final: out = bn2(Y2)relu @ Wl + bl
    k_out<<<gemm_blocks, 256, 0, stream>>>(ag, Wfl, bc + 384, stats + 512, ninv, d_out, N, flags);
}